// Round 6
// baseline (324.172 us; speedup 1.0000x reference)
//
#include <hip/hip_runtime.h>
#include <hip/hip_bf16.h>

#define NUM_AA    20
#define NUM_PAIRS 400
#define DD        64
#define NT        512   // threads per block
#define NW        8     // waves per block
#define LMAX      2048

typedef float f4 __attribute__((ext_vector_type(4)));

// One block per (b, t). Counting-sort positions by pair-bucket; sort buckets
// by member-count (descending). Gather: each wave takes groups of 4 buckets;
// quarter-wave (16 lanes) owns one bucket and loads float4 (full 256B row per
// dwordx4 wave-op). Unroll-by-2 -> 8 dwordx4 in flight within ~48 VGPRs.
// launch_bounds(512,8) caps VGPR at 64 -> 4 blocks/CU, 32 waves/CU.
__global__ __launch_bounds__(NT, 8)
void cksaap_kernel(const int* __restrict__ seq,
                   const float* __restrict__ emb,
                   float* __restrict__ out,
                   int B, int L, int k)
{
    __shared__ int            s_seq[LMAX];       // 8 KB
    __shared__ unsigned short s_idx[LMAX];       // 4 KB
    __shared__ unsigned short s_ord[LMAX];       // 4 KB positions sorted by bucket
    __shared__ unsigned short s_bkt[NUM_PAIRS];  // bucket ids, count-descending
    __shared__ int            s_cnt[NUM_PAIRS];
    __shared__ int            s_off[NUM_PAIRS];
    __shared__ int            s_cur[NUM_PAIRS];
    __shared__ int            s_scan[NT];
    __shared__ int            s_chist[64];
    __shared__ int            s_coff[64];

    const int T   = k + 1;
    const int nwg = gridDim.x;
    const int i   = blockIdx.x;
    int b, t;
    if (nwg == 1024 && T == 4) {
        // XCD-aware: 4 t-blocks of one b land on the same XCD for emb L2 reuse
        const int x = i & 7;
        const int s = i >> 3;
        t = s >> 5;
        b = x * 32 + (s & 31);
    } else {
        b = i / T; t = i % T;
    }

    const int tid  = threadIdx.x;
    const int lane = tid & 63;
    const int wave = tid >> 6;
    const int n    = L - t - 1;

    // phase 1: stage seq row, zero counters
    for (int j = tid; j < L; j += NT) s_seq[j] = seq[(size_t)b * L + j];
    if (tid < NUM_PAIRS) s_cnt[tid] = 0;
    if (tid < 64) s_chist[tid] = 0;
    __syncthreads();

    // phase 2: bucket per position + counts
    for (int j = tid; j < n; j += NT) {
        const int idx = s_seq[j] * NUM_AA + s_seq[j + t + 1];
        s_idx[j] = (unsigned short)idx;
        atomicAdd(&s_cnt[idx], 1);
    }
    __syncthreads();

    // phase 3: exclusive prefix scan of bucket counts (Hillis-Steele over 512)
    const int c0 = (tid < NUM_PAIRS) ? s_cnt[tid] : 0;
    s_scan[tid] = c0;
    __syncthreads();
    for (int off = 1; off < NT; off <<= 1) {
        int v = s_scan[tid];
        if (tid >= off) v += s_scan[tid - off];
        __syncthreads();
        s_scan[tid] = v;
        __syncthreads();
    }
    if (tid < NUM_PAIRS) {
        const int excl = s_scan[tid] - c0;
        s_off[tid] = excl;
        s_cur[tid] = excl;
        atomicAdd(&s_chist[min(c0, 63)], 1);   // count histogram for bucket sort
    }
    __syncthreads();

    // phase 4: scatter position ids into bucket-sorted order
    for (int j = tid; j < n; j += NT) {
        const int idx = s_idx[j];
        const int r   = atomicAdd(&s_cur[idx], 1);
        s_ord[r] = (unsigned short)j;
    }
    // phase 4.5a: descending-order offsets for count bins (suffix sums)
    if (tid < 64) {
        int s = 0;
        for (int c2 = tid + 1; c2 < 64; ++c2) s += s_chist[c2];
        s_coff[tid] = s;
    }
    __syncthreads();
    // phase 4.5b: scatter bucket ids into count-descending order
    if (tid < NUM_PAIRS) {
        const int r = atomicAdd(&s_coff[min(s_cnt[tid], 63)], 1);
        s_bkt[r] = (unsigned short)tid;
    }
    __syncthreads();

    // phase 5: gather. quarter-wave = one bucket, float4 per lane.
    const float  scale   = 0.5f / (float)n;
    const float* embb    = emb + (size_t)b * L * DD;
    float*       outp    = out + ((size_t)b * T + t) * (size_t)(NUM_PAIRS * DD);
    const int    gap     = (t + 1) * DD;
    const int    quarter = lane >> 4;         // 0..3: which bucket of the group
    const int    dlo     = (lane & 15) * 4;   // float index within the row

    for (int g = wave; g < NUM_PAIRS / 4; g += NW) {   // 100 groups
        const int r0  = g * 4;
        const int pid = s_bkt[r0 + quarter];
        const int cc  = s_cnt[pid];
        const int off = s_off[pid];
        const int gmax = s_cnt[s_bkt[r0]];    // descending order => first is max

        f4 acc = {0.0f, 0.0f, 0.0f, 0.0f};
        int m = 0;
        for (; m + 2 <= gmax; m += 2) {
            const bool  ok0 = (m     < cc);
            const bool  ok1 = (m + 1 < cc);
            const int   j0  = ok0 ? (int)s_ord[off + m]     : 0;
            const int   j1  = ok1 ? (int)s_ord[off + m + 1] : 0;
            const float w0  = ok0 ? 1.0f : 0.0f;
            const float w1  = ok1 ? 1.0f : 0.0f;
            const f4 a0 = *(const f4*)&embb[(size_t)j0 * DD + dlo];
            const f4 b0 = *(const f4*)&embb[(size_t)j0 * DD + gap + dlo];
            const f4 a1 = *(const f4*)&embb[(size_t)j1 * DD + dlo];
            const f4 b1 = *(const f4*)&embb[(size_t)j1 * DD + gap + dlo];
            acc += w0 * (a0 + b0) + w1 * (a1 + b1);
        }
        if (m < gmax) {
            const bool  ok0 = (m < cc);
            const int   j0  = ok0 ? (int)s_ord[off + m] : 0;
            const float w0  = ok0 ? 1.0f : 0.0f;
            const f4 a0 = *(const f4*)&embb[(size_t)j0 * DD + dlo];
            const f4 b0 = *(const f4*)&embb[(size_t)j0 * DD + gap + dlo];
            acc += w0 * (a0 + b0);
        }

        *(f4*)&outp[(size_t)pid * DD + dlo] = acc * scale;
    }
}

extern "C" void kernel_launch(void* const* d_in, const int* in_sizes, int n_in,
                              void* d_out, int out_size, void* d_ws, size_t ws_size,
                              hipStream_t stream)
{
    const int*   seq = (const int*)d_in[0];
    const float* emb = (const float*)d_in[1];
    float*       out = (float*)d_out;

    const int B = 256;
    const int L = in_sizes[0] / B;                        // 2048
    const int k = out_size / (B * NUM_PAIRS * DD) - 1;    // 3

    cksaap_kernel<<<B * (k + 1), NT, 0, stream>>>(seq, emb, out, B, L, k);
}

// Round 7
// 302.548 us; speedup vs baseline: 1.0715x; 1.0715x over previous
//
#include <hip/hip_runtime.h>
#include <hip/hip_bf16.h>

#define NUM_AA    20
#define NUM_PAIRS 400
#define DD        64
#define NT        512
#define NW        8
#define LMAX      2048
#define SLICE     16                 // floats of D per block
#define SCALE_F   1048576.0f         // 2^20 fixed-point scale

typedef float f4 __attribute__((ext_vector_type(4)));

// Block = (b, d-slice q). Stream positions in order; for each pair (j, j+t+1)
// load both rows' 16-float slice (partner is L1-adjacent), sum, and scatter
// ONE fixed-point int add per component into a d-major LDS histogram via
// hardware ds_add_u32 (int atomicAdd -- never a CAS loop, unlike float).
// 4 t-passes reuse the 25.6 KB hist; emb re-reads hit L3 (128 MB < 256 MB).
__global__ __launch_bounds__(NT, 8)
void cksaap_kernel(const int* __restrict__ seq,
                   const float* __restrict__ emb,
                   float* __restrict__ out,
                   int B, int L, int k)
{
    __shared__ int s_seq[LMAX];                 // 8 KB
    __shared__ int s_hist[SLICE * NUM_PAIRS];   // 25.6 KB, d-major: [d][p]

    const int T = k + 1;
    const int i = blockIdx.x;
    int b, q;
    if (gridDim.x == 1024) {
        // XCD-aware: the 4 d-slice blocks of one b share cache lines -> same XCD
        const int x = i & 7;
        const int s = i >> 3;        // 0..127
        q = s & 3;
        b = x * 32 + (s >> 2);
    } else {
        b = i >> 2; q = i & 3;
    }

    const int tid  = threadIdx.x;
    const int lane = tid & 63;
    const int wave = tid >> 6;
    const int r    = lane >> 2;     // 0..15: position within 16-row group
    const int c    = lane & 3;      // 0..3:  f4 column within the 16-float slice

    for (int j = tid; j < L; j += NT) s_seq[j] = seq[(size_t)b * L + j];

    const float* embq = emb + (size_t)b * L * DD + q * SLICE;

    for (int t = 0; t < T; ++t) {
        const int n = L - t - 1;
        for (int e = tid; e < SLICE * NUM_PAIRS; e += NT) s_hist[e] = 0;
        __syncthreads();

        // each wave-iteration covers 16 consecutive positions; block covers 128
        #pragma unroll 2
        for (int jb = wave * 16; jb < n; jb += NW * 16) {
            const int  j  = jb + r;
            const bool ok = (j < n);
            const int  jm = ok ? j : (L - 1);
            const int  jp = ok ? (j + t + 1) : (L - 1);
            const int  sa = s_seq[jm];
            const int  sb = s_seq[jp];
            const int  idx = sa * NUM_AA + sb;
            const f4 va = *(const f4*)&embq[(size_t)jm * DD + c * 4];
            const f4 vb = *(const f4*)&embq[(size_t)jp * DD + c * 4];
            const f4 v  = va + vb;
            const float w = ok ? (0.5f * SCALE_F) : 0.0f;
            const int d0 = c * 4;
            atomicAdd(&s_hist[(d0 + 0) * NUM_PAIRS + idx], (int)(v.x * w));
            atomicAdd(&s_hist[(d0 + 1) * NUM_PAIRS + idx], (int)(v.y * w));
            atomicAdd(&s_hist[(d0 + 2) * NUM_PAIRS + idx], (int)(v.z * w));
            atomicAdd(&s_hist[(d0 + 3) * NUM_PAIRS + idx], (int)(v.w * w));
        }
        __syncthreads();

        // store this t-slice: out[b][t][p][q*16 + d]
        const float sc = 1.0f / (SCALE_F * (float)n);
        float* outp = out + ((size_t)b * T + t) * (size_t)(NUM_PAIRS * DD) + q * SLICE;
        for (int e = tid; e < NUM_PAIRS * SLICE; e += NT) {
            const int p = e >> 4;      // bucket
            const int d = e & 15;      // float within slice
            outp[(size_t)p * DD + d] = (float)s_hist[d * NUM_PAIRS + p] * sc;
        }
        __syncthreads();
    }
}

extern "C" void kernel_launch(void* const* d_in, const int* in_sizes, int n_in,
                              void* d_out, int out_size, void* d_ws, size_t ws_size,
                              hipStream_t stream)
{
    const int*   seq = (const int*)d_in[0];
    const float* emb = (const float*)d_in[1];
    float*       out = (float*)d_out;

    const int B = 256;
    const int L = in_sizes[0] / B;                        // 2048
    const int k = out_size / (B * NUM_PAIRS * DD) - 1;    // 3

    cksaap_kernel<<<B * (DD / SLICE), NT, 0, stream>>>(seq, emb, out, B, L, k);
}

// Round 8
// 298.757 us; speedup vs baseline: 1.0851x; 1.0127x over previous
//
#include <hip/hip_runtime.h>
#include <hip/hip_bf16.h>

#define NUM_AA    20
#define NUM_PAIRS 400
#define HSTRIDE   401                // padded: 401 mod 32 = 17 (odd) -> conflict-free banks
#define DD        64
#define NT        512
#define NW        8
#define LMAX      2048
#define SLICE     16                 // floats of D per block
#define SCALE_F   1048576.0f         // 2^20 fixed-point scale

typedef float f4 __attribute__((ext_vector_type(4)));

// Block = (b, d-slice q). Stream positions in order; for each pair (j, j+t+1)
// load both rows' 16-float slice (partner is L1-adjacent), sum, and scatter
// fixed-point int adds into a d-major LDS histogram via hardware ds_add_u32.
// Histogram stride padded 400->401 so bank = (17*d + idx) mod 32 spreads the
// 64 lanes (~2/bank, free) instead of round 7's forced >=4-way conflict.
__global__ __launch_bounds__(NT, 8)
void cksaap_kernel(const int* __restrict__ seq,
                   const float* __restrict__ emb,
                   float* __restrict__ out,
                   int B, int L, int k)
{
    __shared__ int s_seq[LMAX];                 // 8 KB
    __shared__ int s_hist[SLICE * HSTRIDE];     // 25.7 KB, d-major: [d][p], padded

    const int T = k + 1;
    const int i = blockIdx.x;
    int b, q;
    if (gridDim.x == 1024) {
        // XCD-aware: the 4 d-slice blocks of one b share cache lines -> same XCD
        const int x = i & 7;
        const int s = i >> 3;        // 0..127
        q = s & 3;
        b = x * 32 + (s >> 2);
    } else {
        b = i >> 2; q = i & 3;
    }

    const int tid  = threadIdx.x;
    const int lane = tid & 63;
    const int wave = tid >> 6;
    const int r    = lane >> 2;     // 0..15: position within 16-row group
    const int c    = lane & 3;      // 0..3:  f4 column within the 16-float slice

    for (int j = tid; j < L; j += NT) s_seq[j] = seq[(size_t)b * L + j];

    const float* embq = emb + (size_t)b * L * DD + q * SLICE;

    for (int t = 0; t < T; ++t) {
        const int n = L - t - 1;
        for (int e = tid; e < SLICE * HSTRIDE; e += NT) s_hist[e] = 0;
        __syncthreads();

        // each wave-iteration covers 16 consecutive positions; block covers 128
        #pragma unroll 2
        for (int jb = wave * 16; jb < n; jb += NW * 16) {
            const int  j  = jb + r;
            const bool ok = (j < n);
            const int  jm = ok ? j : (L - 1);
            const int  jp = ok ? (j + t + 1) : (L - 1);
            const int  sa = s_seq[jm];
            const int  sb = s_seq[jp];
            const int  idx = sa * NUM_AA + sb;
            const f4 va = *(const f4*)&embq[(size_t)jm * DD + c * 4];
            const f4 vb = *(const f4*)&embq[(size_t)jp * DD + c * 4];
            const f4 v  = va + vb;
            const float w = ok ? (0.5f * SCALE_F) : 0.0f;
            const int d0 = c * 4;
            atomicAdd(&s_hist[(d0 + 0) * HSTRIDE + idx], (int)(v.x * w));
            atomicAdd(&s_hist[(d0 + 1) * HSTRIDE + idx], (int)(v.y * w));
            atomicAdd(&s_hist[(d0 + 2) * HSTRIDE + idx], (int)(v.z * w));
            atomicAdd(&s_hist[(d0 + 3) * HSTRIDE + idx], (int)(v.w * w));
        }
        __syncthreads();

        // store this t-slice: out[b][t][p][q*16 + d]
        const float sc = 1.0f / (SCALE_F * (float)n);
        float* outp = out + ((size_t)b * T + t) * (size_t)(NUM_PAIRS * DD) + q * SLICE;
        for (int e = tid; e < NUM_PAIRS * SLICE; e += NT) {
            const int p = e >> 4;      // bucket
            const int d = e & 15;      // float within slice
            outp[(size_t)p * DD + d] = (float)s_hist[d * HSTRIDE + p] * sc;
        }
        __syncthreads();
    }
}

extern "C" void kernel_launch(void* const* d_in, const int* in_sizes, int n_in,
                              void* d_out, int out_size, void* d_ws, size_t ws_size,
                              hipStream_t stream)
{
    const int*   seq = (const int*)d_in[0];
    const float* emb = (const float*)d_in[1];
    float*       out = (float*)d_out;

    const int B = 256;
    const int L = in_sizes[0] / B;                        // 2048
    const int k = out_size / (B * NUM_PAIRS * DD) - 1;    // 3

    cksaap_kernel<<<B * (DD / SLICE), NT, 0, stream>>>(seq, emb, out, B, L, k);
}